// Round 5
// baseline (654.262 us; speedup 1.0000x reference)
//
#include <hip/hip_runtime.h>
#include <hip/hip_bf16.h>
#include <stdint.h>

#define D 512
#define BATCH 256
#define SEQ 512
// M = BATCH*SEQ = 131072

typedef __attribute__((ext_vector_type(8))) short short8;
typedef __attribute__((ext_vector_type(4))) float floatx4;

__device__ __forceinline__ float bf2f(unsigned short u) {
    union { unsigned int i; float f; } x; x.i = ((unsigned int)u) << 16; return x.f;
}
__device__ __forceinline__ unsigned short f2bf(float f) {
    union { float f; unsigned int i; } x; x.f = f;
    unsigned int i = x.i;
    unsigned int lsb = (i >> 16) & 1u;
    i += 0x7fffu + lsb;
    return (unsigned short)(i >> 16);
}

__device__ __forceinline__ float wred_sum(float v) {
    #pragma unroll
    for (int o = 32; o; o >>= 1) v += __shfl_xor(v, o, 64);
    return v;
}

__device__ __forceinline__ void llds16(const void* g, void* l) {
    auto gp = (const __attribute__((address_space(1))) void*)(g);
    auto lp = (__attribute__((address_space(3))) void*)(uintptr_t)(l);
    __builtin_amdgcn_global_load_lds(gp, lp, 16, 0, 0);
}

// ---------------- scores: raw 10*cos(q, s_row) per row, grid (4, B) ----------------
template<bool F32IN>
__global__ __launch_bounds__(256)
void scores_kernel(const void* __restrict__ s_in_, const float* __restrict__ q,
                   float* __restrict__ scores, unsigned short* __restrict__ s_bf_out) {
    const int b = blockIdx.y;
    const int chunk = blockIdx.x;
    const int t = threadIdx.x, lane = t & 63, wv = t >> 6;

    float qv[8];
    {
        const float4* qp = (const float4*)(q + (size_t)b * D + lane * 8);
        float4 a = qp[0], c = qp[1];
        qv[0] = a.x; qv[1] = a.y; qv[2] = a.z; qv[3] = a.w;
        qv[4] = c.x; qv[5] = c.y; qv[6] = c.z; qv[7] = c.w;
    }
    float qn2 = 0.f;
    #pragma unroll
    for (int j = 0; j < 8; ++j) qn2 += qv[j] * qv[j];
    qn2 = wred_sum(qn2);
    const float qn = sqrtf(qn2);

    const int s0 = chunk * 128 + wv * 32;
    const size_t bbase = (size_t)b * (SEQ * D);
    for (int i = 0; i < 32; ++i) {
        const int s = s0 + i;
        const size_t off = bbase + (size_t)s * D + lane * 8;
        float v[8];
        if (F32IN) {
            const float4* p = (const float4*)((const float*)s_in_ + off);
            float4 a = p[0], c = p[1];
            v[0] = a.x; v[1] = a.y; v[2] = a.z; v[3] = a.w;
            v[4] = c.x; v[5] = c.y; v[6] = c.z; v[7] = c.w;
            short8 w;
            #pragma unroll
            for (int j = 0; j < 8; ++j) w[j] = (short)f2bf(v[j]);
            *(short8*)(s_bf_out + off) = w;
        } else {
            short8 w = *(const short8*)((const unsigned short*)s_in_ + off);
            #pragma unroll
            for (int j = 0; j < 8; ++j) v[j] = bf2f((unsigned short)w[j]);
        }
        float dot = 0.f, nr = 0.f;
        #pragma unroll
        for (int j = 0; j < 8; ++j) {
            dot += v[j] * qv[j];
            nr += v[j] * v[j];
        }
        dot = wred_sum(dot);
        nr  = wred_sum(nr);
        if (lane == 0) {
            scores[b * SEQ + s] = 10.f * dot / fmaxf(qn * sqrtf(nr), 1e-8f);
        }
    }
}

// ---------------- softmax over scores[b][0..511] ----------------
__global__ __launch_bounds__(256)
void softmax_kernel(const float* __restrict__ scores, float* __restrict__ dist_out) {
    const int b = blockIdx.x, t = threadIdx.x, lane = t & 63, wv = t >> 6;
    __shared__ float redbuf[8];
    __shared__ float m_s, sum_s;

    float s0 = scores[b * SEQ + t], s1 = scores[b * SEQ + 256 + t];
    float m = fmaxf(s0, s1);
    #pragma unroll
    for (int o = 32; o; o >>= 1) m = fmaxf(m, __shfl_xor(m, o, 64));
    if (lane == 0) redbuf[wv] = m;
    __syncthreads();
    if (t == 0) m_s = fmaxf(fmaxf(redbuf[0], redbuf[1]), fmaxf(redbuf[2], redbuf[3]));
    __syncthreads();
    const float mm = m_s;
    float e0 = __expf(s0 - mm), e1 = __expf(s1 - mm);
    float es = wred_sum(e0 + e1);
    if (lane == 0) redbuf[wv] = es;
    __syncthreads();
    if (t == 0) sum_s = redbuf[0] + redbuf[1] + redbuf[2] + redbuf[3];
    __syncthreads();
    const float inv = 1.f / sum_s;
    dist_out[b * SEQ + t] = e0 * inv;
    dist_out[b * SEQ + 256 + t] = e1 * inv;
}

// ---------------- GEMM: C = lrelu(A @ W^T + bias) + fused agg partials ----------------
// HBM-bound design: A (no reuse) streams global->VGPR as MFMA fragments with a
// depth-3 register pipeline (backend counts register-dep waits precisely; no
// barriers in the K-loop).  B panel (128 cols) is the only reused operand:
// staged in LDS in two half-K stages (64 KB, rule-21 swizzle), 2 blocks/CU.
// Tile: BM=256 x BN=128, 4 waves; wave = 64 rows x 128 cols (M_rep=4, N_rep=8).
#define GBM 256
#define GBN 128
#define KC 256          // K shorts per B stage
#define NKT 16          // K steps of 32
#define STEPS_PER_STAGE 8

__global__ __launch_bounds__(256, 2)
void gemm_kernel(const unsigned short* __restrict__ A, const unsigned short* __restrict__ Bt,
                 const float* __restrict__ bias, const float* __restrict__ dist,
                 unsigned short* __restrict__ C, float* __restrict__ part) {
    __shared__ __align__(16) unsigned short Bs[GBN * KC];   // 64 KB
    __shared__ float dls[GBM];

    const int tileN = blockIdx.x * GBN;
    const int tileM = blockIdx.y * GBM;
    const int t = threadIdx.x, lane = t & 63, wv = t >> 6;
    const int rr = lane & 15, lg = lane >> 4;
    const int x7 = rr & 7;

    dls[t] = dist[tileM + t];

    // A fragment base: wave wv owns rows [wv*64, wv*64+64)
    const unsigned short* Aw = A + (size_t)(tileM + wv * 64 + rr) * D + lg * 8;

    // B stage: thread t stages chunks f = i*256 + t; f = col*32 + kc.
    // LDS chunk (col, kc) holds global k-chunk (kc ^ (col&7)) of stage k0.
    floatx4 acc[4][8];
    #pragma unroll
    for (int i = 0; i < 4; ++i)
        #pragma unroll
        for (int j = 0; j < 8; ++j) acc[i][j] = {0.f, 0.f, 0.f, 0.f};

    short8 ap[3][4];
    #pragma unroll
    for (int s = 0; s < 3; ++s)
        #pragma unroll
        for (int mi = 0; mi < 4; ++mi)
            ap[s][mi] = *(const short8*)(Aw + (size_t)mi * 16 * D + s * 32);

    // B LDS byte bases per ni (col = ni*16 + rr)
    int bbase[8];
    #pragma unroll
    for (int ni = 0; ni < 8; ++ni) bbase[ni] = (ni * 16 + rr) * KC;   // shorts

    #pragma unroll
    for (int ks = 0; ks < 2; ++ks) {
        if (ks) __syncthreads();            // all waves done reading stage 0
        {
            const int k0 = ks * KC;
            #pragma unroll
            for (int i = 0; i < 16; ++i) {
                const int f = i * 256 + t;
                const int col = f >> 5, kc = f & 31;
                llds16(Bt + (size_t)(tileN + col) * D + k0 + ((kc ^ (col & 7)) << 3),
                       (unsigned short*)Bs + (size_t)f * 8);
            }
        }
        __syncthreads();                    // stage landed (drains vmcnt once)

        #pragma unroll
        for (int ktl = 0; ktl < STEPS_PER_STAGE; ++ktl) {
            const int kt = ks * STEPS_PER_STAGE + ktl;
            // B fragments for this K-step
            short8 bfr[8];
            const int kpart = (((ktl << 2) | lg) ^ x7) << 3;   // shorts
            #pragma unroll
            for (int ni = 0; ni < 8; ++ni)
                bfr[ni] = *(const short8*)&Bs[bbase[ni] + kpart];
            // MFMA consuming register-pipelined A slot kt%3
            #pragma unroll
            for (int mi = 0; mi < 4; ++mi)
                #pragma unroll
                for (int ni = 0; ni < 8; ++ni)
                    acc[mi][ni] = __builtin_amdgcn_mfma_f32_16x16x32_bf16(
                        ap[kt % 3][mi], bfr[ni], acc[mi][ni], 0, 0, 0);
            // refill slot with step kt+3 (register deps keep this safe)
            if (kt + 3 < NKT) {
                #pragma unroll
                for (int mi = 0; mi < 4; ++mi)
                    ap[kt % 3][mi] = *(const short8*)(Aw + (size_t)mi * 16 * D + (kt + 3) * 32);
            }
        }
    }

    // epilogue: bias + leaky relu, scalar bf16 stores, fused per-column agg partial
    const int rgrp = lg;
    const int b = tileM >> 9;
    const int slot = ((blockIdx.y & 1) << 2) + wv;
    #pragma unroll
    for (int ni = 0; ni < 8; ++ni) {
        const int col = tileN + ni * 16 + rr;
        const float bv = bias[col];
        float p = 0.f;
        #pragma unroll
        for (int mi = 0; mi < 4; ++mi) {
            const int rl0 = wv * 64 + mi * 16 + rgrp * 4;
            #pragma unroll
            for (int r2 = 0; r2 < 4; ++r2) {
                float v = acc[mi][ni][r2] + bv;
                v = v >= 0.f ? v : 0.01f * v;
                C[(size_t)(tileM + rl0 + r2) * D + col] = f2bf(v);
                p += dls[rl0 + r2] * v;
            }
        }
        p += __shfl_xor(p, 16, 64);
        p += __shfl_xor(p, 32, 64);
        if (lane < 16) {
            part[(size_t)slot * (BATCH * D) + (size_t)b * D + col] = p;
        }
    }
}

// ---------------- agg partial reduce + residual + LayerNorm ----------------
__global__ __launch_bounds__(256)
void aggln_kernel(const float* __restrict__ part, const float* __restrict__ q_in,
                  const float* __restrict__ gamma, const float* __restrict__ beta,
                  float* __restrict__ q_out) {
    const int b = blockIdx.x, t = threadIdx.x, lane = t & 63, wv = t >> 6;
    __shared__ float red[8];
    __shared__ float mu_s, rstd_s;

    const int c0 = 2 * t;
    float a0 = 0.f, a1 = 0.f;
    #pragma unroll
    for (int slot = 0; slot < 8; ++slot) {
        float2 v = *(const float2*)(part + (size_t)slot * (BATCH * D) + (size_t)b * D + c0);
        a0 += v.x; a1 += v.y;
    }
    float x0 = q_in[b * D + c0] + a0;
    float x1 = q_in[b * D + c0 + 1] + a1;

    float sm = wred_sum(x0 + x1);
    if (lane == 0) red[wv] = sm;
    __syncthreads();
    if (t == 0) mu_s = (red[0] + red[1] + red[2] + red[3]) * (1.f / 512.f);
    __syncthreads();
    const float mu = mu_s;
    float d0 = x0 - mu, d1 = x1 - mu;
    float vv = wred_sum(d0 * d0 + d1 * d1);
    if (lane == 0) red[wv] = vv;
    __syncthreads();
    if (t == 0) rstd_s = rsqrtf((red[0] + red[1] + red[2] + red[3]) * (1.f / 512.f) + 1e-5f);
    __syncthreads();
    const float rs = rstd_s;
    q_out[b * D + c0]     = d0 * rs * gamma[c0]     + beta[c0];
    q_out[b * D + c0 + 1] = d1 * rs * gamma[c0 + 1] + beta[c0 + 1];
}

// ---------------- W f32 -> bf16 ----------------
__global__ __launch_bounds__(256)
void convw_kernel(const float* __restrict__ W, unsigned short* __restrict__ Wb, int n4) {
    int i = blockIdx.x * 256 + threadIdx.x;
    if (i < n4) {
        float4 v = *(const float4*)(W + (size_t)i * 4);
        ushort4 o;
        o.x = f2bf(v.x); o.y = f2bf(v.y); o.z = f2bf(v.z); o.w = f2bf(v.w);
        *(ushort4*)(Wb + (size_t)i * 4) = o;
    }
}

extern "C" void kernel_launch(void* const* d_in, const int* in_sizes, int n_in,
                              void* d_out, int out_size, void* d_ws, size_t ws_size,
                              hipStream_t stream) {
    const float* query = (const float*)d_in[0];
    const float* state = (const float*)d_in[1];
    const float* W     = (const float*)d_in[2];
    const float* bias  = (const float*)d_in[3];
    const float* gamma = (const float*)d_in[4];
    const float* beta  = (const float*)d_in[5];

    float* out_q    = (float*)d_out;
    float* out_dist = (float*)d_out + BATCH * SEQ;

    char* ws = (char*)d_ws;
    const size_t SBYTES = (size_t)BATCH * SEQ * D * 2;   // 134,217,728
    unsigned short* sA = (unsigned short*)ws;
    unsigned short* sB = (unsigned short*)(ws + SBYTES);
    char* ext = ws + 2 * SBYTES;
    float* scores = (float*)ext;                      // 512 KB
    float* dist   = (float*)(ext + 524288);           // 512 KB
    float* qbuf   = (float*)(ext + 2 * 524288);       // 512 KB
    float* part   = (float*)(ext + 3 * 524288);       // 8 * 512 KB = 4 MB
    unsigned short* Wb = (unsigned short*)(ext + 11 * 524288);  // 1.5 MB

    hipMemcpyAsync(qbuf, query, (size_t)BATCH * D * sizeof(float),
                   hipMemcpyDeviceToDevice, stream);
    convw_kernel<<<768, 256, 0, stream>>>(W, Wb, 3 * D * D / 4);

    dim3 sgrid(4, BATCH);
    dim3 gemm_grid(D / GBN, BATCH * SEQ / GBM);   // (4, 512)

    // hop 0
    scores_kernel<true><<<sgrid, 256, 0, stream>>>(state, qbuf, scores, sA);
    softmax_kernel<<<BATCH, 256, 0, stream>>>(scores, dist);
    gemm_kernel<<<gemm_grid, 256, 0, stream>>>(sA, Wb, bias, dist, sB, part);
    aggln_kernel<<<BATCH, 256, 0, stream>>>(part, qbuf, gamma, beta, qbuf);
    // hop 1
    scores_kernel<false><<<sgrid, 256, 0, stream>>>(sB, qbuf, scores, nullptr);
    softmax_kernel<<<BATCH, 256, 0, stream>>>(scores, dist);
    gemm_kernel<<<gemm_grid, 256, 0, stream>>>(sB, Wb + D * D, bias + D, dist, sA, part);
    aggln_kernel<<<BATCH, 256, 0, stream>>>(part, qbuf, gamma, beta, qbuf);
    // hop 2
    scores_kernel<false><<<sgrid, 256, 0, stream>>>(sA, qbuf, scores, nullptr);
    softmax_kernel<<<BATCH, 256, 0, stream>>>(scores, dist);
    gemm_kernel<<<gemm_grid, 256, 0, stream>>>(sA, Wb + 2 * D * D, bias + 2 * D, dist, sB, part);
    aggln_kernel<<<BATCH, 256, 0, stream>>>(part, qbuf, gamma, beta, out_q);
    // final dist
    scores_kernel<false><<<sgrid, 256, 0, stream>>>(sB, out_q, scores, nullptr);
    softmax_kernel<<<BATCH, 256, 0, stream>>>(scores, out_dist);
}